// Round 12
// baseline (226.574 us; speedup 1.0000x reference)
//
#include <hip/hip_runtime.h>
#include <stdint.h>

// LinearAttention. R12 = R11 with compile fix: nontemporal stores go through
// clang ext_vector_type (u32x4), not HIP_vector_type uint4.
// (1) x16 stores non-temporal (bypass L2 - stop evicting x between kernA's
// two reads); (2) ws allocation x16-first with explicit fits-check + fallback
// to R9 path (kernA w/o x16, kernO LDS-dbuf) if ws too small.
// Math: final[b,o,n] = sum_c M_b[o,c] x[b,c,n] + b_out[o]
//   M_b = W_out * blockdiag_h(ctx_h^T) * W_q
//   ctx[hd][e] = (1/Z[hd]) sum_c A[hd][c] Wv[32h+e][c]
//   A[hd][c]   = sum_n exp(k[hd,n]) x[c,n],  Z[hd] = sum_n exp(k[hd,n])
//   k[hd,n]    = sum_c Wk[hd][c] x[c,n]   (k ~ N(0,0.4^2): exp fp32-safe)

#define N_POS 81920   // 80*1024
#define NT    128     // positions per kernA tile
#define TILES 640     // tiles per batch

typedef short bf16x8 __attribute__((ext_vector_type(8)));
typedef float f32x4  __attribute__((ext_vector_type(4)));
typedef uint32_t u32x4 __attribute__((ext_vector_type(4)));

__device__ __forceinline__ uint32_t packbf(float lo, float hi){
  uint32_t a = __float_as_uint(lo), b = __float_as_uint(hi);
  a = (a + 0x8000u) >> 16;
  b = (b + 0x8000u) & 0xffff0000u;
  return a | b;
}
__device__ __forceinline__ short bf16of(float v){
  return (short)((__float_as_uint(v) + 0x8000u) >> 16);
}

// ---------------------------------------------------------------------------
// kernA: per (batch, chunk): partial A[128][64], Z[128] via MFMA.
// If x16 != nullptr, streams staged xs_pc tiles to x16[b][pos][c] bf16 via
// NON-TEMPORAL stores (bypass L2; keep x warm for the second read).
// ---------------------------------------------------------------------------
__global__ __launch_bounds__(512, 4) void kernA(
    const float* __restrict__ x, const float* __restrict__ w,
    float* __restrict__ pA, float* __restrict__ pZ,
    uint16_t* __restrict__ x16, int nch, int tpc)
{
  __shared__ __align__(16) uint16_t xs_cp[64 * 136];   // [c][pos]
  __shared__ __align__(16) uint16_t xs_pc[128 * 72];   // [pos][c]
  __shared__ __align__(16) uint16_t es[128 * 136];     // [hd][pos]

  const int t  = threadIdx.x;
  const int w8 = t >> 6;     // wave 0..7
  const int l  = t & 63;
  const int lm = l & 15;
  const int lg = l >> 4;

  const int b  = blockIdx.x / nch;
  const int ch = blockIdx.x % nch;
  const float* xb = x + (size_t)b * 64 * N_POS;

  const int rr  = t >> 3;        // xs_cp: c row 0..63
  const int pg  = t & 7;         // xs_cp: 16-pos group
  const int spp = t & 127;       // xs_pc: pos
  const int scg = t >> 7;        // xs_pc: c-group (16 c)

  const int pth = w8 & 3;
  const int ht0 = (w8 >> 2) * 4;

  bf16x8 wkf[4][2];
  #pragma unroll
  for (int i = 0; i < 4; ++i)
    #pragma unroll
    for (int kk = 0; kk < 2; ++kk){
      const float* wp = w + (size_t)(128 + 16*(ht0+i) + lm) * 64 + 32*kk + 8*lg;
      float4 w0 = *(const float4*)wp;
      float4 w1 = *(const float4*)(wp + 4);
      bf16x8 f;
      f[0]=bf16of(w0.x); f[1]=bf16of(w0.y); f[2]=bf16of(w0.z); f[3]=bf16of(w0.w);
      f[4]=bf16of(w1.x); f[5]=bf16of(w1.y); f[6]=bf16of(w1.z); f[7]=bf16of(w1.w);
      wkf[i][kk] = f;
    }

  bf16x8 ones;
  #pragma unroll
  for (int j = 0; j < 8; ++j) ones[j] = (short)0x3F80;   // bf16 1.0

  f32x4 acc[4], zac;
  zac = (f32x4){0.f,0.f,0.f,0.f};
  #pragma unroll
  for (int n = 0; n < 4; ++n) acc[n] = (f32x4){0.f,0.f,0.f,0.f};

  float4 fa0, fa1, fa2, fa3;
  float v[16];
  {
    const int n0 = (ch * tpc) * NT;
    const float* ga = xb + (size_t)rr * N_POS + n0 + 16*pg;
    fa0 = *(const float4*)ga;       fa1 = *(const float4*)(ga + 4);
    fa2 = *(const float4*)(ga + 8); fa3 = *(const float4*)(ga + 12);
    const float* gb = xb + (size_t)(16*scg) * N_POS + n0 + spp;
    #pragma unroll
    for (int i = 0; i < 16; ++i) v[i] = gb[(size_t)i * N_POS];
  }

  for (int tile = 0; tile < tpc; ++tile){
    const int n0 = (ch * tpc + tile) * NT;
    __syncthreads();
    {
      uint4 u0, u1;
      u0.x = packbf(fa0.x,fa0.y); u0.y = packbf(fa0.z,fa0.w);
      u0.z = packbf(fa1.x,fa1.y); u0.w = packbf(fa1.z,fa1.w);
      u1.x = packbf(fa2.x,fa2.y); u1.y = packbf(fa2.z,fa2.w);
      u1.z = packbf(fa3.x,fa3.y); u1.w = packbf(fa3.z,fa3.w);
      *(uint4*)&xs_cp[rr*136 + 16*pg]     = u0;
      *(uint4*)&xs_cp[rr*136 + 16*pg + 8] = u1;
      uint4 p0, p1;
      p0.x = packbf(v[0],v[1]);   p0.y = packbf(v[2],v[3]);
      p0.z = packbf(v[4],v[5]);   p0.w = packbf(v[6],v[7]);
      p1.x = packbf(v[8],v[9]);   p1.y = packbf(v[10],v[11]);
      p1.z = packbf(v[12],v[13]); p1.w = packbf(v[14],v[15]);
      *(uint4*)&xs_pc[spp*72 + 16*scg]     = p0;
      *(uint4*)&xs_pc[spp*72 + 16*scg + 8] = p1;
    }
    __syncthreads();
    // issue next tile's loads (hide HBM latency under phase1+phase2)
    if (tile + 1 < tpc){
      const int n1 = n0 + NT;
      const float* ga = xb + (size_t)rr * N_POS + n1 + 16*pg;
      fa0 = *(const float4*)ga;       fa1 = *(const float4*)(ga + 4);
      fa2 = *(const float4*)(ga + 8); fa3 = *(const float4*)(ga + 12);
      const float* gb = xb + (size_t)(16*scg) * N_POS + n1 + spp;
      #pragma unroll
      for (int i = 0; i < 16; ++i) v[i] = gb[(size_t)i * N_POS];
    }
    // stream xs_pc -> x16[b][pos][c], NON-TEMPORAL (bypass L2)
    if (x16){
      const int pos = t >> 2, q = t & 3;
      u32x4 q0 = *(const u32x4*)&xs_pc[pos*72 + 16*q];
      u32x4 q1 = *(const u32x4*)&xs_pc[pos*72 + 16*q + 8];
      uint16_t* dst = x16 + ((size_t)b * N_POS + n0 + pos) * 64 + 16*q;
      __builtin_nontemporal_store(q0, (u32x4*)&dst[0]);
      __builtin_nontemporal_store(q1, (u32x4*)&dst[8]);
    }
    // phase1: S[pos][hd] -> E=exp -> es[hd][pos]
    #pragma unroll
    for (int ip = 0; ip < 2; ++ip){
      const int pt = pth + 4*ip;
      bf16x8 af0 = *(const bf16x8*)&xs_pc[(16*pt + lm)*72 + 8*lg];
      bf16x8 af1 = *(const bf16x8*)&xs_pc[(16*pt + lm)*72 + 32 + 8*lg];
      #pragma unroll
      for (int i = 0; i < 4; ++i){
        f32x4 s = (f32x4){0.f,0.f,0.f,0.f};
        s = __builtin_amdgcn_mfma_f32_16x16x32_bf16(af0, wkf[i][0], s, 0,0,0);
        s = __builtin_amdgcn_mfma_f32_16x16x32_bf16(af1, wkf[i][1], s, 0,0,0);
        float e0 = __expf(s[0]), e1 = __expf(s[1]);
        float e2 = __expf(s[2]), e3 = __expf(s[3]);
        uint2 pk; pk.x = packbf(e0,e1); pk.y = packbf(e2,e3);
        *(uint2*)&es[(16*(ht0+i) + lm)*136 + 16*pt + 4*lg] = pk;
      }
    }
    __syncthreads();
    // phase2: wave w8 owns hd rows 16w8..16w8+15; K = 128 pos in 4 chunks
    __builtin_amdgcn_s_setprio(1);
    #pragma unroll
    for (int kk = 0; kk < 4; ++kk){
      bf16x8 ea = *(const bf16x8*)&es[(16*w8 + lm)*136 + 32*kk + 8*lg];
      bf16x8 xbf[4];
      #pragma unroll
      for (int n = 0; n < 4; ++n)
        xbf[n] = *(const bf16x8*)&xs_cp[(16*n + lm)*136 + 32*kk + 8*lg];
      #pragma unroll
      for (int n = 0; n < 4; ++n)
        acc[n] = __builtin_amdgcn_mfma_f32_16x16x32_bf16(ea, xbf[n], acc[n], 0,0,0);
      zac = __builtin_amdgcn_mfma_f32_16x16x32_bf16(ea, ones, zac, 0,0,0);
    }
    __builtin_amdgcn_s_setprio(0);
  }

  float* pa = pA + (size_t)blockIdx.x * 8192;
  const int hd0 = 16*w8 + 4*lg;
  #pragma unroll
  for (int n = 0; n < 4; ++n)
    #pragma unroll
    for (int r = 0; r < 4; ++r)
      pa[(size_t)(hd0 + r)*64 + 16*n + lm] = acc[n][r];
  if (lm == 0){
    #pragma unroll
    for (int r = 0; r < 4; ++r)
      pZ[(size_t)blockIdx.x * 128 + hd0 + r] = zac[r];
  }
}

// ---------------------------------------------------------------------------
// kernR1: parallel reduce of partials. grid 64 = 8 batches x 8 slices.
// ---------------------------------------------------------------------------
__global__ __launch_bounds__(256) void kernR1(
    const float* __restrict__ pA, const float* __restrict__ pZ,
    float* __restrict__ Ar, float* __restrict__ Zr, int nch)
{
  const int b = blockIdx.x >> 3, s = blockIdx.x & 7;
  const int off = s * 1024 + threadIdx.x * 4;
  float4 a = make_float4(0.f, 0.f, 0.f, 0.f);
  for (int ch = 0; ch < nch; ++ch){
    float4 v = *(const float4*)&pA[(size_t)(b * nch + ch) * 8192 + off];
    a.x += v.x; a.y += v.y; a.z += v.z; a.w += v.w;
  }
  *(float4*)&Ar[(size_t)b * 8192 + off] = a;
  if (s == 0 && threadIdx.x < 128){
    float z = 0.f;
    for (int ch = 0; ch < nch; ++ch) z += pZ[(size_t)(b * nch + ch) * 128 + threadIdx.x];
    Zr[b * 128 + threadIdx.x] = z;
  }
}

// ---------------------------------------------------------------------------
// kernCM (fused R2+M): per batch: ctx -> T -> M
// ---------------------------------------------------------------------------
__global__ __launch_bounds__(256) void kernCM(
    const float* __restrict__ Ar, const float* __restrict__ Zr,
    const float* __restrict__ w_qkv, const float* __restrict__ w_out,
    float* __restrict__ M)
{
  __shared__ float A[128 * 65];
  __shared__ float Z[128];
  __shared__ float cs[128 * 33];
  __shared__ float T[64 * 129];
  const int b = blockIdx.x, t = threadIdx.x;

  #pragma unroll
  for (int k = 0; k < 32; ++k){
    int i = t + 256 * k;
    A[(i >> 6) * 65 + (i & 63)] = Ar[(size_t)b * 8192 + i];
  }
  if (t < 128) Z[t] = Zr[b * 128 + t];
  __syncthreads();

  {
    const int hd = t & 127, h = hd >> 5, e0 = (t >> 7) * 16;
    const float rz = 1.0f / Z[hd];
    for (int je = 0; je < 16; ++je){
      int e = e0 + je;
      const float* wv = w_qkv + (size_t)(256 + 32 * h + e) * 64;   // Wv row
      float a = 0.f;
      #pragma unroll
      for (int c = 0; c < 64; ++c) a = fmaf(A[hd * 65 + c], wv[c], a);
      cs[hd * 33 + e] = a * rz;
    }
  }
  __syncthreads();

  const int o = t & 63, g = t >> 6;
  for (int jh = 0; jh < 32; ++jh){
    int hd = 32 * g + jh;
    const float* wo = w_out + (size_t)o * 128 + 32 * g;
    float a = 0.f;
    #pragma unroll
    for (int e = 0; e < 32; ++e) a = fmaf(wo[e], cs[hd * 33 + e], a);
    T[o * 129 + hd] = a;
  }
  __syncthreads();

  const int c0 = 16 * g;
  float m[16];
  #pragma unroll
  for (int j = 0; j < 16; ++j) m[j] = 0.f;
  for (int hd = 0; hd < 128; ++hd){
    float tv = T[o * 129 + hd];
    const float* wq = w_qkv + (size_t)hd * 64 + c0;
    #pragma unroll
    for (int j = 0; j < 16; ++j) m[j] = fmaf(tv, wq[j], m[j]);
  }
  #pragma unroll
  for (int j = 0; j < 16; ++j) M[(size_t)b * 4096 + o * 64 + c0 + j] = m[j];
}

// ---------------------------------------------------------------------------
// kernO v5: no LDS, no barrier. A-fragments = direct b128 loads from
// x16[pos][c] (wave consumes 16 contiguous 128B rows -> full sectors).
// ---------------------------------------------------------------------------
__global__ __launch_bounds__(256, 4) void kernO(
    const uint16_t* __restrict__ x16, const float* __restrict__ M,
    const float* __restrict__ b_out, float* __restrict__ out)
{
  const int t  = threadIdx.x;
  const int wv = t >> 6;
  const int l  = t & 63;
  const int lm = l & 15;
  const int lg = l >> 4;

  const int b  = blockIdx.x / 320;
  const int p0 = (blockIdx.x % 320) * 256;
  const uint16_t* xb = x16 + ((size_t)b * N_POS + p0) * 64;

  const float* Mb = M + (size_t)b * 4096;
  bf16x8 mb[4][2];
  float bias[4];
  #pragma unroll
  for (int ot = 0; ot < 4; ++ot){
    bias[ot] = b_out[16*ot + lm];
    #pragma unroll
    for (int kk = 0; kk < 2; ++kk){
      const float* mp = Mb + (size_t)(16*ot + lm)*64 + 32*kk + 8*lg;
      float4 m0 = *(const float4*)mp;
      float4 m1 = *(const float4*)(mp + 4);
      bf16x8 f;
      f[0]=bf16of(m0.x); f[1]=bf16of(m0.y); f[2]=bf16of(m0.z); f[3]=bf16of(m0.w);
      f[4]=bf16of(m1.x); f[5]=bf16of(m1.y); f[6]=bf16of(m1.z); f[7]=bf16of(m1.w);
      mb[ot][kk] = f;
    }
  }

  bf16x8 af0[4], af1[4];
  #pragma unroll
  for (int ip = 0; ip < 4; ++ip){
    const int row = 16*(4*wv + ip) + lm;
    af0[ip] = *(const bf16x8*)&xb[row*64 + 8*lg];
    af1[ip] = *(const bf16x8*)&xb[row*64 + 32 + 8*lg];
  }

  float* ob = out + (size_t)b * 64 * N_POS + p0;

  #pragma unroll
  for (int ip = 0; ip < 4; ++ip){
    const int pt = 4*wv + ip;
    #pragma unroll
    for (int ot = 0; ot < 4; ++ot){
      f32x4 d = (f32x4){0.f,0.f,0.f,0.f};
      d = __builtin_amdgcn_mfma_f32_16x16x32_bf16(af0[ip], mb[ot][0], d, 0,0,0);
      d = __builtin_amdgcn_mfma_f32_16x16x32_bf16(af1[ip], mb[ot][1], d, 0,0,0);
      float4 st = make_float4(d[0]+bias[ot], d[1]+bias[ot],
                              d[2]+bias[ot], d[3]+bias[ot]);
      *(float4*)&ob[(size_t)(16*ot + lm) * N_POS + 16*pt + 4*lg] = st;
    }
  }
}

// ---------------------------------------------------------------------------
// kernO_f32 (fallback, R9): staged LDS double-buffer from fp32 x.
// ---------------------------------------------------------------------------
__global__ __launch_bounds__(256, 2) void kernO_f32(
    const float* __restrict__ x, const float* __restrict__ M,
    const float* __restrict__ b_out, float* __restrict__ out)
{
  __shared__ __align__(16) uint16_t xs[2][256 * 72];

  const int t  = threadIdx.x;
  const int wv = t >> 6;
  const int l  = t & 63;
  const int lm = l & 15;
  const int lg = l >> 4;

  const int b  = blockIdx.x >> 6;
  const int tg = blockIdx.x & 63;
  const float* xb = x   + (size_t)b * 64 * N_POS + tg * 1280;
  float*       ob = out + (size_t)b * 64 * N_POS + tg * 1280;

  const float* Mb = M + (size_t)b * 4096;
  bf16x8 mb[4][2];
  float bias[4];
  #pragma unroll
  for (int ot = 0; ot < 4; ++ot){
    bias[ot] = b_out[16*ot + lm];
    #pragma unroll
    for (int kk = 0; kk < 2; ++kk){
      const float* mp = Mb + (size_t)(16*ot + lm)*64 + 32*kk + 8*lg;
      float4 m0 = *(const float4*)mp;
      float4 m1 = *(const float4*)(mp + 4);
      bf16x8 f;
      f[0]=bf16of(m0.x); f[1]=bf16of(m0.y); f[2]=bf16of(m0.z); f[3]=bf16of(m0.w);
      f[4]=bf16of(m1.x); f[5]=bf16of(m1.y); f[6]=bf16of(m1.z); f[7]=bf16of(m1.w);
      mb[ot][kk] = f;
    }
  }

  uint4 st[8];
  #pragma unroll
  for (int cc = 0; cc < 8; ++cc){
    float v[8];
    #pragma unroll
    for (int j = 0; j < 8; ++j)
      v[j] = xb[(size_t)(8*cc + j) * N_POS + t];
    st[cc].x = packbf(v[0],v[1]); st[cc].y = packbf(v[2],v[3]);
    st[cc].z = packbf(v[4],v[5]); st[cc].w = packbf(v[6],v[7]);
  }
  #pragma unroll
  for (int cc = 0; cc < 8; ++cc)
    *(uint4*)&xs[0][t*72 + 8*cc] = st[cc];
  __syncthreads();

  for (int tile = 0; tile < 5; ++tile){
    const int cur = tile & 1;
    if (tile < 4){
      const float* gn = xb + (tile + 1) * 256 + t;
      #pragma unroll
      for (int cc = 0; cc < 8; ++cc){
        float v[8];
        #pragma unroll
        for (int j = 0; j < 8; ++j)
          v[j] = gn[(size_t)(8*cc + j) * N_POS];
        st[cc].x = packbf(v[0],v[1]); st[cc].y = packbf(v[2],v[3]);
        st[cc].z = packbf(v[4],v[5]); st[cc].w = packbf(v[6],v[7]);
      }
    }
    const int pp0 = tile * 256;
    #pragma unroll
    for (int ip = 0; ip < 4; ++ip){
      const int pt = 4*wv + ip;
      bf16x8 af0 = *(const bf16x8*)&xs[cur][(16*pt + lm)*72 + 8*lg];
      bf16x8 af1 = *(const bf16x8*)&xs[cur][(16*pt + lm)*72 + 32 + 8*lg];
      #pragma unroll
      for (int ot = 0; ot < 4; ++ot){
        f32x4 d = (f32x4){0.f,0.f,0.f,0.f};
        d = __builtin_amdgcn_mfma_f32_16x16x32_bf16(af0, mb[ot][0], d, 0,0,0);
        d = __builtin_amdgcn_mfma_f32_16x16x32_bf16(af1, mb[ot][1], d, 0,0,0);
        float4 stv = make_float4(d[0]+bias[ot], d[1]+bias[ot],
                                 d[2]+bias[ot], d[3]+bias[ot]);
        *(float4*)&ob[(size_t)(16*ot + lm) * N_POS + pp0 + 16*pt + 4*lg] = stv;
      }
    }
    if (tile < 4){
      #pragma unroll
      for (int cc = 0; cc < 8; ++cc)
        *(uint4*)&xs[cur ^ 1][t*72 + 8*cc] = st[cc];
      __syncthreads();
    }
  }
}

// ---------------------------------------------------------------------------
extern "C" void kernel_launch(void* const* d_in, const int* in_sizes, int n_in,
                              void* d_out, int out_size, void* d_ws, size_t ws_size,
                              hipStream_t stream)
{
  const float* x     = (const float*)d_in[0];
  const float* w_qkv = (const float*)d_in[1];
  const float* w_out = (const float*)d_in[2];
  const float* b_out = (const float*)d_in[3];
  float* out = (float*)d_out;
  float* ws  = (float*)d_ws;

  const size_t x16_bytes = (size_t)8 * N_POS * 64 * 2;          // 84 MB
  const size_t fixed     = ((size_t)8*8192 + 8*128 + 8*4096) * 4;
  const size_t part64    = (size_t)8 * 64 * (8192 + 128) * 4;   // 17 MB

  const bool use16 = (x16_bytes + fixed + part64) <= ws_size;

  if (use16){
    const int nch = 64, tpc = TILES / 64;
    uint16_t* x16 = (uint16_t*)ws;
    float* pA  = (float*)(ws + x16_bytes / 4);   // ws is float*; x16_bytes/4 floats
    float* pZ  = pA + (size_t)8 * nch * 8192;
    float* Ar  = pZ + (size_t)8 * nch * 128;
    float* Zr  = Ar + (size_t)8 * 8192;
    float* M   = Zr + (size_t)8 * 128;

    kernA<<<8 * nch, 512, 0, stream>>>(x, w_qkv, pA, pZ, x16, nch, tpc);
    kernR1<<<64,     256, 0, stream>>>(pA, pZ, Ar, Zr, nch);
    kernCM<<<8,      256, 0, stream>>>(Ar, Zr, w_qkv, w_out, M);
    kernO<<<2560,    256, 0, stream>>>(x16, M, b_out, out);
  } else {
    static const int cand[] = {64, 40, 32, 20, 16, 10, 8, 5, 4, 2, 1};
    int nch = 1;
    for (int i = 0; i < 11; ++i){
      size_t need = ((size_t)8 * cand[i] * (8192 + 128)) * 4 + fixed;
      if (need <= ws_size){ nch = cand[i]; break; }
    }
    const int tpc = TILES / nch;
    float* pA  = ws;
    float* pZ  = pA + (size_t)8 * nch * 8192;
    float* Ar  = pZ + (size_t)8 * nch * 128;
    float* Zr  = Ar + (size_t)8 * 8192;
    float* M   = Zr + (size_t)8 * 128;

    kernA<<<8 * nch, 512, 0, stream>>>(x, w_qkv, pA, pZ, nullptr, nch, tpc);
    kernR1<<<64,     256, 0, stream>>>(pA, pZ, Ar, Zr, nch);
    kernCM<<<8,      256, 0, stream>>>(Ar, Zr, w_qkv, w_out, M);
    kernO_f32<<<512, 256, 0, stream>>>(x, M, b_out, out);
  }
}

// Round 13
// 209.424 us; speedup vs baseline: 1.0819x; 1.0819x over previous
//
#include <hip/hip_runtime.h>
#include <stdint.h>

// LinearAttention. R13: kernA drops the 16-dword strided v-gather; xs_pc is
// built LDS->LDS from xs_cp (conflict-free u16 reads + b128 writes). x16
// stores back to REGULAR (NT measured worse). kernO v5 (x16-direct) kept.
// Math: final[b,o,n] = sum_c M_b[o,c] x[b,c,n] + b_out[o]
//   M_b = W_out * blockdiag_h(ctx_h^T) * W_q
//   ctx[hd][e] = (1/Z[hd]) sum_c A[hd][c] Wv[32h+e][c]
//   A[hd][c]   = sum_n exp(k[hd,n]) x[c,n],  Z[hd] = sum_n exp(k[hd,n])
//   k[hd,n]    = sum_c Wk[hd][c] x[c,n]   (k ~ N(0,0.4^2): exp fp32-safe)

#define N_POS 81920   // 80*1024
#define NT    128     // positions per kernA tile
#define TILES 640     // tiles per batch

typedef short bf16x8 __attribute__((ext_vector_type(8)));
typedef float f32x4  __attribute__((ext_vector_type(4)));

__device__ __forceinline__ uint32_t packbf(float lo, float hi){
  uint32_t a = __float_as_uint(lo), b = __float_as_uint(hi);
  a = (a + 0x8000u) >> 16;
  b = (b + 0x8000u) & 0xffff0000u;
  return a | b;
}
__device__ __forceinline__ short bf16of(float v){
  return (short)((__float_as_uint(v) + 0x8000u) >> 16);
}

// ---------------------------------------------------------------------------
// kernA: per (batch, chunk): partial A[128][64], Z[128] via MFMA.
// Per tile: fa-loads (4x float4/thread, full tile read ONCE) -> xs_cp;
// xs_pc built LDS->LDS (16 conflict-free u16 reads + 2 b128 writes);
// x16 (if non-null) streamed from xs_pc with regular stores.
// Barriers: A(reuse guard) stage B build C phase1 D phase2.
// ---------------------------------------------------------------------------
__global__ __launch_bounds__(512, 4) void kernA(
    const float* __restrict__ x, const float* __restrict__ w,
    float* __restrict__ pA, float* __restrict__ pZ,
    uint16_t* __restrict__ x16, int nch, int tpc)
{
  __shared__ __align__(16) uint16_t xs_cp[64 * 136];   // [c][pos]
  __shared__ __align__(16) uint16_t xs_pc[128 * 72];   // [pos][c]
  __shared__ __align__(16) uint16_t es[128 * 136];     // [hd][pos]

  const int t  = threadIdx.x;
  const int w8 = t >> 6;     // wave 0..7
  const int l  = t & 63;
  const int lm = l & 15;
  const int lg = l >> 4;

  const int b  = blockIdx.x / nch;
  const int ch = blockIdx.x % nch;
  const float* xb = x + (size_t)b * 64 * N_POS;

  // fa staging roles
  const int rr = t >> 3;         // c row 0..63
  const int pg = t & 7;          // 16-pos group
  // xs_pc build roles (within-wave pos spans 64 consecutive -> bank-free)
  const int pos_b = t & 127;     // pos 0..127
  const int cg_b  = t >> 7;      // c-group of 16

  const int pth = w8 & 3;
  const int ht0 = (w8 >> 2) * 4;

  bf16x8 wkf[4][2];
  #pragma unroll
  for (int i = 0; i < 4; ++i)
    #pragma unroll
    for (int kk = 0; kk < 2; ++kk){
      const float* wp = w + (size_t)(128 + 16*(ht0+i) + lm) * 64 + 32*kk + 8*lg;
      float4 w0 = *(const float4*)wp;
      float4 w1 = *(const float4*)(wp + 4);
      bf16x8 f;
      f[0]=bf16of(w0.x); f[1]=bf16of(w0.y); f[2]=bf16of(w0.z); f[3]=bf16of(w0.w);
      f[4]=bf16of(w1.x); f[5]=bf16of(w1.y); f[6]=bf16of(w1.z); f[7]=bf16of(w1.w);
      wkf[i][kk] = f;
    }

  bf16x8 ones;
  #pragma unroll
  for (int j = 0; j < 8; ++j) ones[j] = (short)0x3F80;   // bf16 1.0

  f32x4 acc[4], zac;
  zac = (f32x4){0.f,0.f,0.f,0.f};
  #pragma unroll
  for (int n = 0; n < 4; ++n) acc[n] = (f32x4){0.f,0.f,0.f,0.f};

  // prefetch tile 0 (fa only — single full-tile read)
  float4 fa0, fa1, fa2, fa3;
  {
    const int n0 = (ch * tpc) * NT;
    const float* ga = xb + (size_t)rr * N_POS + n0 + 16*pg;
    fa0 = *(const float4*)ga;       fa1 = *(const float4*)(ga + 4);
    fa2 = *(const float4*)(ga + 8); fa3 = *(const float4*)(ga + 12);
  }

  for (int tile = 0; tile < tpc; ++tile){
    const int n0 = (ch * tpc + tile) * NT;
    __syncthreads();   // A: prev phase1/phase2/x16 done with cp/pc/es
    // stage xs_cp from fa regs
    {
      uint4 u0, u1;
      u0.x = packbf(fa0.x,fa0.y); u0.y = packbf(fa0.z,fa0.w);
      u0.z = packbf(fa1.x,fa1.y); u0.w = packbf(fa1.z,fa1.w);
      u1.x = packbf(fa2.x,fa2.y); u1.y = packbf(fa2.z,fa2.w);
      u1.z = packbf(fa3.x,fa3.y); u1.w = packbf(fa3.z,fa3.w);
      *(uint4*)&xs_cp[rr*136 + 16*pg]     = u0;
      *(uint4*)&xs_cp[rr*136 + 16*pg + 8] = u1;
    }
    __syncthreads();   // B: xs_cp ready
    // issue next tile's fa loads (hide HBM latency under build+phases)
    if (tile + 1 < tpc){
      const int n1 = n0 + NT;
      const float* ga = xb + (size_t)rr * N_POS + n1 + 16*pg;
      fa0 = *(const float4*)ga;       fa1 = *(const float4*)(ga + 4);
      fa2 = *(const float4*)(ga + 8); fa3 = *(const float4*)(ga + 12);
    }
    // build xs_pc[pos][c] from xs_cp (16 u16 reads, conflict-free; 2 b128 wr)
    {
      uint32_t d[8];
      #pragma unroll
      for (int i = 0; i < 8; ++i){
        uint32_t e0 = xs_cp[(16*cg_b + 2*i    )*136 + pos_b];
        uint32_t e1 = xs_cp[(16*cg_b + 2*i + 1)*136 + pos_b];
        d[i] = e0 | (e1 << 16);
      }
      uint4 q0, q1;
      q0.x = d[0]; q0.y = d[1]; q0.z = d[2]; q0.w = d[3];
      q1.x = d[4]; q1.y = d[5]; q1.z = d[6]; q1.w = d[7];
      *(uint4*)&xs_pc[pos_b*72 + 16*cg_b]     = q0;
      *(uint4*)&xs_pc[pos_b*72 + 16*cg_b + 8] = q1;
    }
    __syncthreads();   // C: xs_pc ready
    // stream xs_pc -> x16[b][pos][c] (regular stores; 2KB contiguous/wave)
    if (x16){
      const int pos = t >> 2, q = t & 3;
      uint4 q0 = *(const uint4*)&xs_pc[pos*72 + 16*q];
      uint4 q1 = *(const uint4*)&xs_pc[pos*72 + 16*q + 8];
      uint16_t* dst = x16 + ((size_t)b * N_POS + n0 + pos) * 64 + 16*q;
      *(uint4*)&dst[0] = q0;
      *(uint4*)&dst[8] = q1;
    }
    // phase1: S[pos][hd] -> E=exp -> es[hd][pos]
    #pragma unroll
    for (int ip = 0; ip < 2; ++ip){
      const int pt = pth + 4*ip;
      bf16x8 af0 = *(const bf16x8*)&xs_pc[(16*pt + lm)*72 + 8*lg];
      bf16x8 af1 = *(const bf16x8*)&xs_pc[(16*pt + lm)*72 + 32 + 8*lg];
      #pragma unroll
      for (int i = 0; i < 4; ++i){
        f32x4 s = (f32x4){0.f,0.f,0.f,0.f};
        s = __builtin_amdgcn_mfma_f32_16x16x32_bf16(af0, wkf[i][0], s, 0,0,0);
        s = __builtin_amdgcn_mfma_f32_16x16x32_bf16(af1, wkf[i][1], s, 0,0,0);
        float e0 = __expf(s[0]), e1 = __expf(s[1]);
        float e2 = __expf(s[2]), e3 = __expf(s[3]);
        uint2 pk; pk.x = packbf(e0,e1); pk.y = packbf(e2,e3);
        *(uint2*)&es[(16*(ht0+i) + lm)*136 + 16*pt + 4*lg] = pk;
      }
    }
    __syncthreads();   // D: es ready
    // phase2: wave w8 owns hd rows 16w8..16w8+15; K = 128 pos in 4 chunks
    __builtin_amdgcn_s_setprio(1);
    #pragma unroll
    for (int kk = 0; kk < 4; ++kk){
      bf16x8 ea = *(const bf16x8*)&es[(16*w8 + lm)*136 + 32*kk + 8*lg];
      bf16x8 xbf[4];
      #pragma unroll
      for (int n = 0; n < 4; ++n)
        xbf[n] = *(const bf16x8*)&xs_cp[(16*n + lm)*136 + 32*kk + 8*lg];
      #pragma unroll
      for (int n = 0; n < 4; ++n)
        acc[n] = __builtin_amdgcn_mfma_f32_16x16x32_bf16(ea, xbf[n], acc[n], 0,0,0);
      zac = __builtin_amdgcn_mfma_f32_16x16x32_bf16(ea, ones, zac, 0,0,0);
    }
    __builtin_amdgcn_s_setprio(0);
  }

  float* pa = pA + (size_t)blockIdx.x * 8192;
  const int hd0 = 16*w8 + 4*lg;
  #pragma unroll
  for (int n = 0; n < 4; ++n)
    #pragma unroll
    for (int r = 0; r < 4; ++r)
      pa[(size_t)(hd0 + r)*64 + 16*n + lm] = acc[n][r];
  if (lm == 0){
    #pragma unroll
    for (int r = 0; r < 4; ++r)
      pZ[(size_t)blockIdx.x * 128 + hd0 + r] = zac[r];
  }
}

// ---------------------------------------------------------------------------
// kernR1: parallel reduce of partials. grid 64 = 8 batches x 8 slices.
// ---------------------------------------------------------------------------
__global__ __launch_bounds__(256) void kernR1(
    const float* __restrict__ pA, const float* __restrict__ pZ,
    float* __restrict__ Ar, float* __restrict__ Zr, int nch)
{
  const int b = blockIdx.x >> 3, s = blockIdx.x & 7;
  const int off = s * 1024 + threadIdx.x * 4;
  float4 a = make_float4(0.f, 0.f, 0.f, 0.f);
  for (int ch = 0; ch < nch; ++ch){
    float4 v = *(const float4*)&pA[(size_t)(b * nch + ch) * 8192 + off];
    a.x += v.x; a.y += v.y; a.z += v.z; a.w += v.w;
  }
  *(float4*)&Ar[(size_t)b * 8192 + off] = a;
  if (s == 0 && threadIdx.x < 128){
    float z = 0.f;
    for (int ch = 0; ch < nch; ++ch) z += pZ[(size_t)(b * nch + ch) * 128 + threadIdx.x];
    Zr[b * 128 + threadIdx.x] = z;
  }
}

// ---------------------------------------------------------------------------
// kernCM (fused R2+M): per batch: ctx -> T -> M
// ---------------------------------------------------------------------------
__global__ __launch_bounds__(256) void kernCM(
    const float* __restrict__ Ar, const float* __restrict__ Zr,
    const float* __restrict__ w_qkv, const float* __restrict__ w_out,
    float* __restrict__ M)
{
  __shared__ float A[128 * 65];
  __shared__ float Z[128];
  __shared__ float cs[128 * 33];
  __shared__ float T[64 * 129];
  const int b = blockIdx.x, t = threadIdx.x;

  #pragma unroll
  for (int k = 0; k < 32; ++k){
    int i = t + 256 * k;
    A[(i >> 6) * 65 + (i & 63)] = Ar[(size_t)b * 8192 + i];
  }
  if (t < 128) Z[t] = Zr[b * 128 + t];
  __syncthreads();

  {
    const int hd = t & 127, h = hd >> 5, e0 = (t >> 7) * 16;
    const float rz = 1.0f / Z[hd];
    for (int je = 0; je < 16; ++je){
      int e = e0 + je;
      const float* wv = w_qkv + (size_t)(256 + 32 * h + e) * 64;   // Wv row
      float a = 0.f;
      #pragma unroll
      for (int c = 0; c < 64; ++c) a = fmaf(A[hd * 65 + c], wv[c], a);
      cs[hd * 33 + e] = a * rz;
    }
  }
  __syncthreads();

  const int o = t & 63, g = t >> 6;
  for (int jh = 0; jh < 32; ++jh){
    int hd = 32 * g + jh;
    const float* wo = w_out + (size_t)o * 128 + 32 * g;
    float a = 0.f;
    #pragma unroll
    for (int e = 0; e < 32; ++e) a = fmaf(wo[e], cs[hd * 33 + e], a);
    T[o * 129 + hd] = a;
  }
  __syncthreads();

  const int c0 = 16 * g;
  float m[16];
  #pragma unroll
  for (int j = 0; j < 16; ++j) m[j] = 0.f;
  for (int hd = 0; hd < 128; ++hd){
    float tv = T[o * 129 + hd];
    const float* wq = w_qkv + (size_t)hd * 64 + c0;
    #pragma unroll
    for (int j = 0; j < 16; ++j) m[j] = fmaf(tv, wq[j], m[j]);
  }
  #pragma unroll
  for (int j = 0; j < 16; ++j) M[(size_t)b * 4096 + o * 64 + c0 + j] = m[j];
}

// ---------------------------------------------------------------------------
// kernO v5: no LDS, no barrier. A-fragments = direct b128 loads from
// x16[pos][c] (wave consumes 16 contiguous 128B rows -> full sectors).
// ---------------------------------------------------------------------------
__global__ __launch_bounds__(256, 4) void kernO(
    const uint16_t* __restrict__ x16, const float* __restrict__ M,
    const float* __restrict__ b_out, float* __restrict__ out)
{
  const int t  = threadIdx.x;
  const int wv = t >> 6;
  const int l  = t & 63;
  const int lm = l & 15;
  const int lg = l >> 4;

  const int b  = blockIdx.x / 320;
  const int p0 = (blockIdx.x % 320) * 256;
  const uint16_t* xb = x16 + ((size_t)b * N_POS + p0) * 64;

  const float* Mb = M + (size_t)b * 4096;
  bf16x8 mb[4][2];
  float bias[4];
  #pragma unroll
  for (int ot = 0; ot < 4; ++ot){
    bias[ot] = b_out[16*ot + lm];
    #pragma unroll
    for (int kk = 0; kk < 2; ++kk){
      const float* mp = Mb + (size_t)(16*ot + lm)*64 + 32*kk + 8*lg;
      float4 m0 = *(const float4*)mp;
      float4 m1 = *(const float4*)(mp + 4);
      bf16x8 f;
      f[0]=bf16of(m0.x); f[1]=bf16of(m0.y); f[2]=bf16of(m0.z); f[3]=bf16of(m0.w);
      f[4]=bf16of(m1.x); f[5]=bf16of(m1.y); f[6]=bf16of(m1.z); f[7]=bf16of(m1.w);
      mb[ot][kk] = f;
    }
  }

  bf16x8 af0[4], af1[4];
  #pragma unroll
  for (int ip = 0; ip < 4; ++ip){
    const int row = 16*(4*wv + ip) + lm;
    af0[ip] = *(const bf16x8*)&xb[row*64 + 8*lg];
    af1[ip] = *(const bf16x8*)&xb[row*64 + 32 + 8*lg];
  }

  float* ob = out + (size_t)b * 64 * N_POS + p0;

  #pragma unroll
  for (int ip = 0; ip < 4; ++ip){
    const int pt = 4*wv + ip;
    #pragma unroll
    for (int ot = 0; ot < 4; ++ot){
      f32x4 d = (f32x4){0.f,0.f,0.f,0.f};
      d = __builtin_amdgcn_mfma_f32_16x16x32_bf16(af0[ip], mb[ot][0], d, 0,0,0);
      d = __builtin_amdgcn_mfma_f32_16x16x32_bf16(af1[ip], mb[ot][1], d, 0,0,0);
      float4 st = make_float4(d[0]+bias[ot], d[1]+bias[ot],
                              d[2]+bias[ot], d[3]+bias[ot]);
      *(float4*)&ob[(size_t)(16*ot + lm) * N_POS + 16*pt + 4*lg] = st;
    }
  }
}

// ---------------------------------------------------------------------------
// kernO_f32 (fallback): staged LDS double-buffer from fp32 x.
// ---------------------------------------------------------------------------
__global__ __launch_bounds__(256, 2) void kernO_f32(
    const float* __restrict__ x, const float* __restrict__ M,
    const float* __restrict__ b_out, float* __restrict__ out)
{
  __shared__ __align__(16) uint16_t xs[2][256 * 72];

  const int t  = threadIdx.x;
  const int wv = t >> 6;
  const int l  = t & 63;
  const int lm = l & 15;
  const int lg = l >> 4;

  const int b  = blockIdx.x >> 6;
  const int tg = blockIdx.x & 63;
  const float* xb = x   + (size_t)b * 64 * N_POS + tg * 1280;
  float*       ob = out + (size_t)b * 64 * N_POS + tg * 1280;

  const float* Mb = M + (size_t)b * 4096;
  bf16x8 mb[4][2];
  float bias[4];
  #pragma unroll
  for (int ot = 0; ot < 4; ++ot){
    bias[ot] = b_out[16*ot + lm];
    #pragma unroll
    for (int kk = 0; kk < 2; ++kk){
      const float* mp = Mb + (size_t)(16*ot + lm)*64 + 32*kk + 8*lg;
      float4 m0 = *(const float4*)mp;
      float4 m1 = *(const float4*)(mp + 4);
      bf16x8 f;
      f[0]=bf16of(m0.x); f[1]=bf16of(m0.y); f[2]=bf16of(m0.z); f[3]=bf16of(m0.w);
      f[4]=bf16of(m1.x); f[5]=bf16of(m1.y); f[6]=bf16of(m1.z); f[7]=bf16of(m1.w);
      mb[ot][kk] = f;
    }
  }

  uint4 st[8];
  #pragma unroll
  for (int cc = 0; cc < 8; ++cc){
    float v[8];
    #pragma unroll
    for (int j = 0; j < 8; ++j)
      v[j] = xb[(size_t)(8*cc + j) * N_POS + t];
    st[cc].x = packbf(v[0],v[1]); st[cc].y = packbf(v[2],v[3]);
    st[cc].z = packbf(v[4],v[5]); st[cc].w = packbf(v[6],v[7]);
  }
  #pragma unroll
  for (int cc = 0; cc < 8; ++cc)
    *(uint4*)&xs[0][t*72 + 8*cc] = st[cc];
  __syncthreads();

  for (int tile = 0; tile < 5; ++tile){
    const int cur = tile & 1;
    if (tile < 4){
      const float* gn = xb + (tile + 1) * 256 + t;
      #pragma unroll
      for (int cc = 0; cc < 8; ++cc){
        float v[8];
        #pragma unroll
        for (int j = 0; j < 8; ++j)
          v[j] = gn[(size_t)(8*cc + j) * N_POS];
        st[cc].x = packbf(v[0],v[1]); st[cc].y = packbf(v[2],v[3]);
        st[cc].z = packbf(v[4],v[5]); st[cc].w = packbf(v[6],v[7]);
      }
    }
    const int pp0 = tile * 256;
    #pragma unroll
    for (int ip = 0; ip < 4; ++ip){
      const int pt = 4*wv + ip;
      bf16x8 af0 = *(const bf16x8*)&xs[cur][(16*pt + lm)*72 + 8*lg];
      bf16x8 af1 = *(const bf16x8*)&xs[cur][(16*pt + lm)*72 + 32 + 8*lg];
      #pragma unroll
      for (int ot = 0; ot < 4; ++ot){
        f32x4 d = (f32x4){0.f,0.f,0.f,0.f};
        d = __builtin_amdgcn_mfma_f32_16x16x32_bf16(af0, mb[ot][0], d, 0,0,0);
        d = __builtin_amdgcn_mfma_f32_16x16x32_bf16(af1, mb[ot][1], d, 0,0,0);
        float4 stv = make_float4(d[0]+bias[ot], d[1]+bias[ot],
                                 d[2]+bias[ot], d[3]+bias[ot]);
        *(float4*)&ob[(size_t)(16*ot + lm) * N_POS + pp0 + 16*pt + 4*lg] = stv;
      }
    }
    if (tile < 4){
      #pragma unroll
      for (int cc = 0; cc < 8; ++cc)
        *(uint4*)&xs[cur ^ 1][t*72 + 8*cc] = st[cc];
      __syncthreads();
    }
  }
}

// ---------------------------------------------------------------------------
extern "C" void kernel_launch(void* const* d_in, const int* in_sizes, int n_in,
                              void* d_out, int out_size, void* d_ws, size_t ws_size,
                              hipStream_t stream)
{
  const float* x     = (const float*)d_in[0];
  const float* w_qkv = (const float*)d_in[1];
  const float* w_out = (const float*)d_in[2];
  const float* b_out = (const float*)d_in[3];
  float* out = (float*)d_out;
  float* ws  = (float*)d_ws;

  const size_t x16_bytes = (size_t)8 * N_POS * 64 * 2;          // 84 MB
  const size_t fixed     = ((size_t)8*8192 + 8*128 + 8*4096) * 4;
  const size_t part64    = (size_t)8 * 64 * (8192 + 128) * 4;   // 17 MB

  const bool use16 = (x16_bytes + fixed + part64) <= ws_size;

  if (use16){
    const int nch = 64, tpc = TILES / 64;
    uint16_t* x16 = (uint16_t*)ws;
    float* pA  = (float*)(ws + x16_bytes / 4);
    float* pZ  = pA + (size_t)8 * nch * 8192;
    float* Ar  = pZ + (size_t)8 * nch * 128;
    float* Zr  = Ar + (size_t)8 * 8192;
    float* M   = Zr + (size_t)8 * 128;

    kernA<<<8 * nch, 512, 0, stream>>>(x, w_qkv, pA, pZ, x16, nch, tpc);
    kernR1<<<64,     256, 0, stream>>>(pA, pZ, Ar, Zr, nch);
    kernCM<<<8,      256, 0, stream>>>(Ar, Zr, w_qkv, w_out, M);
    kernO<<<2560,    256, 0, stream>>>(x16, M, b_out, out);
  } else {
    static const int cand[] = {64, 40, 32, 20, 16, 10, 8, 5, 4, 2, 1};
    int nch = 1;
    for (int i = 0; i < 11; ++i){
      size_t need = ((size_t)8 * cand[i] * (8192 + 128)) * 4 + fixed;
      if (need <= ws_size){ nch = cand[i]; break; }
    }
    const int tpc = TILES / nch;
    float* pA  = ws;
    float* pZ  = pA + (size_t)8 * nch * 8192;
    float* Ar  = pZ + (size_t)8 * nch * 128;
    float* Zr  = Ar + (size_t)8 * 8192;
    float* M   = Zr + (size_t)8 * 128;

    kernA<<<8 * nch, 512, 0, stream>>>(x, w_qkv, pA, pZ, nullptr, nch, tpc);
    kernR1<<<64,     256, 0, stream>>>(pA, pZ, Ar, Zr, nch);
    kernCM<<<8,      256, 0, stream>>>(Ar, Zr, w_qkv, w_out, M);
    kernO_f32<<<512, 256, 0, stream>>>(x, M, b_out, out);
  }
}